// Round 4
// baseline (287.090 us; speedup 1.0000x reference)
//
#include <hip/hip_runtime.h>
#include <hip/hip_bf16.h>

#define S_LEN 4096
#define HID 768
#define NHEAD 12
#define HL 64

typedef __attribute__((ext_vector_type(8))) short short8;
typedef __attribute__((ext_vector_type(4))) float f32x4;
using bf16 = __hip_bfloat16;

__device__ __forceinline__ void gl2lds16(const void* g, void* l) {
  __builtin_amdgcn_global_load_lds((__attribute__((address_space(1))) void*)(g),
                                   (__attribute__((address_space(3))) void*)(l),
                                   16, 0, 0);
}

__device__ __forceinline__ f32x4 mfma_bf16(short8 a, short8 b, f32x4 c) {
  return __builtin_amdgcn_mfma_f32_16x16x32_bf16(a, b, c, 0, 0, 0);
}

__device__ __forceinline__ void storeC(float* C, long idx, float v) { C[idx] = v; }
__device__ __forceinline__ void storeC(bf16* C, long idx, float v) { C[idx] = __float2bfloat16(v); }

// lgkmcnt(0)-only barrier: drains LDS ops but NOT vmcnt, so global register
// prefetch loads stay in flight across the barrier.
#define BAR() asm volatile("s_waitcnt lgkmcnt(0)\n\ts_barrier" ::: "memory")

// ---------------- fp32 -> bf16 convert (x + 4 weights, fused) ----------------
__global__ __launch_bounds__(256) void cvt_all(
    const float* __restrict__ x, const float* __restrict__ wq,
    const float* __restrict__ wk, const float* __restrict__ wv,
    const float* __restrict__ wfc, bf16* __restrict__ xb, bf16* __restrict__ wqb,
    bf16* __restrict__ wkb, bf16* __restrict__ wvb, bf16* __restrict__ wfcb) {
  const long NX = (long)S_LEN * HID;
  const long NW = (long)HID * HID;
  long i = ((long)blockIdx.x * 256 + threadIdx.x) * 4;
  const float* src;
  bf16* dst;
  long off;
  if (i < NX) {
    src = x; dst = xb; off = i;
  } else {
    long j = i - NX;
    int wsel = (int)(j / NW);
    off = j - (long)wsel * NW;
    src = wsel == 0 ? wq : wsel == 1 ? wk : wsel == 2 ? wv : wfc;
    dst = wsel == 0 ? wqb : wsel == 1 ? wkb : wsel == 2 ? wvb : wfcb;
  }
  float4 v = *(const float4*)(src + off);
  bf16 h0 = __float2bfloat16(v.x), h1 = __float2bfloat16(v.y);
  bf16 h2 = __float2bfloat16(v.z), h3 = __float2bfloat16(v.w);
  ushort4 o;
  o.x = *(unsigned short*)&h0; o.y = *(unsigned short*)&h1;
  o.z = *(unsigned short*)&h2; o.w = *(unsigned short*)&h3;
  *(ushort4*)(dst + off) = o;
}

// ---------------- GEMM: C[M x 768] = scale * A[M x 768] * B[768 x 768]^T ------
template <typename OT>
__global__ __launch_bounds__(256) void gemm_bt(
    const bf16* __restrict__ A, const bf16* __restrict__ B0,
    const bf16* __restrict__ B1, const bf16* __restrict__ B2,
    OT* __restrict__ C0, OT* __restrict__ C1, OT* __restrict__ C2, float qscale) {
  constexpr int K = HID;
  __shared__ __align__(16) bf16 As[128 * 32];
  __shared__ __align__(16) bf16 Bs[128 * 32];
  const int z = blockIdx.z;
  const bf16* B = (z == 0) ? B0 : (z == 1) ? B1 : B2;
  OT* C = (z == 0) ? C0 : (z == 1) ? C1 : C2;
  const float sc = (z == 0) ? qscale : 1.0f;
  const int bm = blockIdx.y, bn = blockIdx.x;
  const int t = threadIdx.x, lane = t & 63, w = t >> 6;
  const int wm = w >> 1, wn = w & 1;
  const int q4 = lane >> 4, c16 = lane & 15;
  const int srow = lane >> 2, scol = (lane & 3) * 8;
  const bf16* Ab = A + (long)bm * 128 * K;
  const bf16* Bb = B + (long)bn * 128 * K;
  f32x4 acc[4][4] = {};
  for (int k0 = 0; k0 < K; k0 += 32) {
#pragma unroll
    for (int r = 0; r < 2; ++r) {
      int rowb = r * 64 + w * 16;
      gl2lds16(Ab + (long)(rowb + srow) * K + k0 + scol, &As[rowb * 32]);
      gl2lds16(Bb + (long)(rowb + srow) * K + k0 + scol, &Bs[rowb * 32]);
    }
    __syncthreads();
    short8 af[4], bfv[4];
#pragma unroll
    for (int i = 0; i < 4; ++i)
      af[i] = *(const short8*)&As[(wm * 64 + i * 16 + c16) * 32 + q4 * 8];
#pragma unroll
    for (int j = 0; j < 4; ++j)
      bfv[j] = *(const short8*)&Bs[(wn * 64 + j * 16 + c16) * 32 + q4 * 8];
#pragma unroll
    for (int i = 0; i < 4; ++i)
#pragma unroll
      for (int j = 0; j < 4; ++j)
        acc[i][j] = mfma_bf16(af[i], bfv[j], acc[i][j]);
    __syncthreads();
  }
  const long crow0 = (long)bm * 128 + wm * 64;
  const int ccol0 = bn * 128 + wn * 64;
#pragma unroll
  for (int i = 0; i < 4; ++i)
#pragma unroll
    for (int j = 0; j < 4; ++j)
#pragma unroll
      for (int r = 0; r < 4; ++r) {
        long row = crow0 + i * 16 + q4 * 4 + r;
        int col = ccol0 + j * 16 + c16;
        storeC(C, row * HID + col, sc * acc[i][j][r]);
      }
}

// ---------------- final GEMM: 128x64 tile ----------------
__global__ __launch_bounds__(256) void gemm_fc(const bf16* __restrict__ A,
                                               const bf16* __restrict__ B,
                                               float* __restrict__ C) {
  __shared__ __align__(16) bf16 As[128 * 32];
  __shared__ __align__(16) bf16 Bs[64 * 32];
  const int bm = blockIdx.y, bn = blockIdx.x;
  const int t = threadIdx.x, lane = t & 63, w = t >> 6;
  const int q4 = lane >> 4, c16 = lane & 15;
  const int srow = lane >> 2, scol = (lane & 3) * 8;
  const bf16* Ab = A + (long)bm * 128 * HID;
  const bf16* Bb = B + (long)bn * 64 * HID;
  f32x4 acc[2][4] = {};
  for (int k0 = 0; k0 < HID; k0 += 32) {
#pragma unroll
    for (int r = 0; r < 2; ++r) {
      int rowb = w * 32 + r * 16;
      gl2lds16(Ab + (long)(rowb + srow) * HID + k0 + scol, &As[rowb * 32]);
    }
    gl2lds16(Bb + (long)(w * 16 + srow) * HID + k0 + scol, &Bs[w * 16 * 32]);
    __syncthreads();
    short8 af[2], bfv[4];
#pragma unroll
    for (int i = 0; i < 2; ++i)
      af[i] = *(const short8*)&As[(w * 32 + i * 16 + c16) * 32 + q4 * 8];
#pragma unroll
    for (int j = 0; j < 4; ++j)
      bfv[j] = *(const short8*)&Bs[(j * 16 + c16) * 32 + q4 * 8];
#pragma unroll
    for (int i = 0; i < 2; ++i)
#pragma unroll
      for (int j = 0; j < 4; ++j)
        acc[i][j] = mfma_bf16(af[i], bfv[j], acc[i][j]);
    __syncthreads();
  }
#pragma unroll
  for (int i = 0; i < 2; ++i)
#pragma unroll
    for (int j = 0; j < 4; ++j)
#pragma unroll
      for (int r = 0; r < 4; ++r) {
        long row = (long)bm * 128 + w * 32 + i * 16 + q4 * 4 + r;
        int col = bn * 64 + j * 16 + c16;
        C[row * HID + col] = acc[i][j][r];
      }
}

// ---------------- V transpose: [4096][768] -> [768][4096] ----------------
__global__ __launch_bounds__(256) void transpose_v(const bf16* __restrict__ V,
                                                   bf16* __restrict__ Vt) {
  __shared__ unsigned short tile[64][65];
  const int bs = blockIdx.x * 64;
  const int be = blockIdx.y * 64;
  const int t = threadIdx.x;
#pragma unroll
  for (int p = 0; p < 4; ++p) {
    int i = p * 256 + t;
    int r = i >> 4;
    int c = (i & 15) * 4;
    ushort4 v = *(const ushort4*)((const unsigned short*)V + (long)(bs + r) * HID + be + c);
    tile[r][c] = v.x; tile[r][c + 1] = v.y; tile[r][c + 2] = v.z; tile[r][c + 3] = v.w;
  }
  __syncthreads();
#pragma unroll
  for (int p = 0; p < 4; ++p) {
    int i = p * 256 + t;
    int r = i >> 4;
    int c = (i & 15) * 4;
    ushort4 v;
    v.x = tile[c][r]; v.y = tile[c + 1][r]; v.z = tile[c + 2][r]; v.w = tile[c + 3][r];
    *(ushort4*)((unsigned short*)Vt + (long)(be + r) * S_LEN + bs + c) = v;
  }
}

// ---------------- flash attention v4: kv-split + 1 barrier/iter ---------------
// grid (qt 64, head 12, split 2). Each block handles 32 kv-tiles; with fixed
// m=0 (no-max softmax, scores pre-scaled & bounded) the partial (O,l) of the
// two splits are directly additive -> combine kernel does (O0+O1)/(l0+l1).
// Per iter: S^T=K.Q^T (kv-split across waves) -> exp2 -> P to LDS (XOR-swizzled
// double buffer) -> ONE barrier -> O^T += V^T.P^T (d-split). K frags reloaded
// right after their last use (S), V frags right after PV: next-gen global loads
// are in flight across the barrier (BAR drains lgkm only).
__global__ __launch_bounds__(256, 5) void flash_attn(
    const bf16* __restrict__ Q, const bf16* __restrict__ Kg,
    const bf16* __restrict__ Vt, float* __restrict__ Opart,
    float* __restrict__ Lpart) {
  __shared__ __align__(16) bf16 Ps[2][64 * 64];  // [q][kv-swizzled], 16 KB
  __shared__ float Lred[4][64];
  const int qt = blockIdx.x, h = blockIdx.y, sp = blockIdx.z;
  const int t = threadIdx.x, lane = t & 63, w = t >> 6;
  const int q4 = lane >> 4, c16 = lane & 15;
  const int s0 = qt * 64;
  const int e7 = c16 & 7;  // row-swizzle key (q & 7 == c16 & 7 for all our rows)

  // Q B-frags, loop-invariant: row q = s0 + j*16 + c16, k-chunk = ks*32 + q4*8
  short8 qf[2][4];
  {
    const bf16* Qb = Q + (long)(s0 + c16) * HID + h * HL + q4 * 8;
#pragma unroll
    for (int j = 0; j < 4; ++j)
#pragma unroll
      for (int ks = 0; ks < 2; ++ks)
        qf[ks][j] = *(const short8*)(Qb + (long)j * 16 * HID + ks * 32);
  }
  // K A-frag base: row kv = sp*2048 + kt*64 + w*16 + c16, k = ks*32 + q4*8
  const bf16* kp = Kg + (long)(sp * 2048 + w * 16 + c16) * HID + h * HL + q4 * 8;
  // V^T A-frag base: row d = w*16 + c16, k (kv) = sp*2048 + kt*64 + ks*32 + q4*8
  const bf16* vp = Vt + (long)(h * HL + w * 16 + c16) * S_LEN + sp * 2048 + q4 * 8;

  float l_part[4] = {0.f, 0.f, 0.f, 0.f};
  f32x4 o_acc[4] = {};
  short8 kf0 = *(const short8*)(kp), kf1 = *(const short8*)(kp + 32);
  short8 vf0 = *(const short8*)(vp), vf1 = *(const short8*)(vp + 32);

  // write slot: chunk (w*2 + (q4>>1)) ^ e7, half (q4&1)
  const int wr_off = ((w * 2 + (q4 >> 1)) ^ e7) * 8 + (q4 & 1) * 4;

  for (int kt = 0; kt < 32; ++kt) {
    bf16* Pb = Ps[kt & 1];
    // ---- S^T = K . Q^T ----
    f32x4 sacc[4] = {};
#pragma unroll
    for (int j = 0; j < 4; ++j) sacc[j] = mfma_bf16(kf0, qf[0][j], sacc[j]);
#pragma unroll
    for (int j = 0; j < 4; ++j) sacc[j] = mfma_bf16(kf1, qf[1][j], sacc[j]);

    // ---- prefetch next K frags (kf just had its last use) ----
    const bf16* kpn = (kt == 31) ? kp : kp + 64 * HID;
    kf0 = *(const short8*)(kpn);
    kf1 = *(const short8*)(kpn + 32);
    kp = kpn;

    // ---- p = exp2(s); partial l; P -> LDS (swizzled) ----
#pragma unroll
    for (int j = 0; j < 4; ++j) {
      float p0 = __builtin_amdgcn_exp2f(sacc[j][0]);
      float p1 = __builtin_amdgcn_exp2f(sacc[j][1]);
      float p2 = __builtin_amdgcn_exp2f(sacc[j][2]);
      float p3 = __builtin_amdgcn_exp2f(sacc[j][3]);
      l_part[j] += (p0 + p1) + (p2 + p3);
      bf16 b0 = __float2bfloat16(p0), b1 = __float2bfloat16(p1);
      bf16 b2 = __float2bfloat16(p2), b3 = __float2bfloat16(p3);
      short4 pk;
      pk.x = *(short*)&b0; pk.y = *(short*)&b1; pk.z = *(short*)&b2; pk.w = *(short*)&b3;
      *(short4*)&Pb[(j * 16 + c16) * 64 + wr_off] = pk;
    }
    BAR();  // P visible; K/V prefetch vmcnt NOT drained

    // ---- O^T += V^T . P^T ----
#pragma unroll
    for (int ks = 0; ks < 2; ++ks) {
      short8 vfk = ks ? vf1 : vf0;
#pragma unroll
      for (int j = 0; j < 4; ++j) {
        short8 pf = *(const short8*)&Pb[(j * 16 + c16) * 64 + ((ks * 4 + q4) ^ e7) * 8];
        o_acc[j] = mfma_bf16(vfk, pf, o_acc[j]);
      }
    }
    // ---- prefetch next V frags (vf just had its last use) ----
    const bf16* vpn = (kt == 31) ? vp : vp + 64;
    vf0 = *(const short8*)(vpn);
    vf1 = *(const short8*)(vpn + 32);
    vp = vpn;
    // no second barrier: next iter writes the other Ps buffer
  }

  // ---- l reduction: quad-sum over kv then cross-wave via LDS ----
#pragma unroll
  for (int j = 0; j < 4; ++j) {
    float s = l_part[j];
    s += __shfl_xor(s, 16, 64);
    s += __shfl_xor(s, 32, 64);
    Lred[w][j * 16 + c16] = s;
  }
  __syncthreads();
  const long bb = (long)(sp * 64 + qt) * NHEAD + h;
#pragma unroll
  for (int j = 0; j < 4; ++j) {
    int q = j * 16 + c16;
    float lt = Lred[0][q] + Lred[1][q] + Lred[2][q] + Lred[3][q];
    if (w == 0) Lpart[bb * 64 + q] = lt;  // q4-duplicate stores: benign
    float4 st;
    st.x = o_acc[j][0]; st.y = o_acc[j][1]; st.z = o_acc[j][2]; st.w = o_acc[j][3];
    *(float4*)&Opart[bb * 4096 + (long)q * 64 + w * 16 + q4 * 4] = st;
  }
}

// ---------------- combine: O = (O0 + O1) / (l0 + l1) -> bf16 ----------------
__global__ __launch_bounds__(256) void combine(const float* __restrict__ Opart,
                                               const float* __restrict__ Lpart,
                                               bf16* __restrict__ Ob) {
  const int qt = blockIdx.x, h = blockIdx.y;
  const long b0 = (long)qt * NHEAD + h;
  const long b1 = (long)(64 + qt) * NHEAD + h;
  const int t = threadIdx.x;
  const int q = t >> 2, dc = (t & 3) * 16;
  const float rl = 1.0f / (Lpart[b0 * 64 + q] + Lpart[b1 * 64 + q]);
  const float* p0 = Opart + b0 * 4096 + (long)q * 64 + dc;
  const float* p1 = Opart + b1 * 4096 + (long)q * 64 + dc;
  bf16* ob = Ob + (long)(qt * 64 + q) * HID + h * HL + dc;
#pragma unroll
  for (int half = 0; half < 2; ++half) {
    short8 pk;
#pragma unroll
    for (int i = 0; i < 2; ++i) {
      float4 a = *(const float4*)(p0 + half * 8 + i * 4);
      float4 b = *(const float4*)(p1 + half * 8 + i * 4);
      float v0 = (a.x + b.x) * rl, v1 = (a.y + b.y) * rl;
      float v2 = (a.z + b.z) * rl, v3 = (a.w + b.w) * rl;
      bf16 h0 = __float2bfloat16(v0), h1 = __float2bfloat16(v1);
      bf16 h2 = __float2bfloat16(v2), h3 = __float2bfloat16(v3);
      pk[i * 4 + 0] = *(short*)&h0; pk[i * 4 + 1] = *(short*)&h1;
      pk[i * 4 + 2] = *(short*)&h2; pk[i * 4 + 3] = *(short*)&h3;
    }
    *(short8*)(ob + half * 8) = pk;
  }
}

extern "C" void kernel_launch(void* const* d_in, const int* in_sizes, int n_in,
                              void* d_out, int out_size, void* d_ws, size_t ws_size,
                              hipStream_t stream) {
  const float* x = (const float*)d_in[0];
  const float* wq = (const float*)d_in[1];
  const float* wk = (const float*)d_in[2];
  const float* wv = (const float*)d_in[3];
  const float* wfc = (const float*)d_in[4];
  float* out = (float*)d_out;

  const long NBIG = (long)S_LEN * HID * sizeof(bf16);  // 6.29 MB
  const long NWB = (long)HID * HID * sizeof(bf16);     // 1.18 MB
  char* p = (char*)d_ws;
  // persistent region
  bf16* wfcb = (bf16*)p; p += NWB;
  bf16* Qb = (bf16*)p;   p += NBIG;
  bf16* Kb = (bf16*)p;   p += NBIG;
  bf16* Vtb = (bf16*)p;  p += NBIG;
  bf16* Ob = (bf16*)p;   p += NBIG;
  // scratch region (phase A: xb/wq/wk/wv/Vb; phase B overlays: Opart/Lpart)
  char* scratch = p;
  bf16* xb = (bf16*)p;   p += NBIG;
  bf16* wqb = (bf16*)p;  p += NWB;
  bf16* wkb = (bf16*)p;  p += NWB;
  bf16* wvb = (bf16*)p;  p += NWB;
  bf16* Vb = (bf16*)p;
  float* Opart = (float*)scratch;                       // 2*64*12*4096 f32 = 25.2 MB
  float* Lpart = (float*)(scratch + (long)2 * 64 * NHEAD * 4096 * sizeof(float));

  const float c1 = 0.125f * 1.44269504088896340736f;  // softmax scale * log2(e)

  const long total4 = ((long)S_LEN * HID + 4L * HID * HID) / 4;
  cvt_all<<<(int)(total4 / 256), 256, 0, stream>>>(x, wq, wk, wv, wfc, xb, wqb, wkb,
                                                   wvb, wfcb);
  gemm_bt<bf16><<<dim3(HID / 128, S_LEN / 128, 3), 256, 0, stream>>>(
      xb, wqb, wkb, wvb, Qb, Kb, Vb, c1);
  transpose_v<<<dim3(S_LEN / 64, HID / 64), 256, 0, stream>>>(Vb, Vtb);
  flash_attn<<<dim3(S_LEN / 64, NHEAD, 2), 256, 0, stream>>>(Qb, Kb, Vtb, Opart,
                                                             Lpart);
  combine<<<dim3(S_LEN / 64, NHEAD), 256, 0, stream>>>(Opart, Lpart, Ob);
  gemm_fc<<<dim3(HID / 64, S_LEN / 128), 256, 0, stream>>>(Ob, wfcb, out);
}

// Round 5
// 210.996 us; speedup vs baseline: 1.3606x; 1.3606x over previous
//
#include <hip/hip_runtime.h>
#include <hip/hip_bf16.h>

#define S_LEN 4096
#define HID 768
#define NHEAD 12
#define HL 64

typedef __attribute__((ext_vector_type(8))) short short8;
typedef __attribute__((ext_vector_type(4))) float f32x4;
using bf16 = __hip_bfloat16;

__device__ __forceinline__ void gl2lds16(const void* g, void* l) {
  __builtin_amdgcn_global_load_lds((__attribute__((address_space(1))) void*)(g),
                                   (__attribute__((address_space(3))) void*)(l),
                                   16, 0, 0);
}

__device__ __forceinline__ f32x4 mfma_bf16(short8 a, short8 b, f32x4 c) {
  return __builtin_amdgcn_mfma_f32_16x16x32_bf16(a, b, c, 0, 0, 0);
}

__device__ __forceinline__ void storeC(float* C, long idx, float v) { C[idx] = v; }
__device__ __forceinline__ void storeC(bf16* C, long idx, float v) { C[idx] = __float2bfloat16(v); }

// lgkmcnt(0)-only barrier: drains LDS ops but NOT vmcnt, so global register
// prefetch loads stay in flight across the barrier.
#define BAR() asm volatile("s_waitcnt lgkmcnt(0)\n\ts_barrier" ::: "memory")

// ---------------- fp32 -> bf16 convert (x + 4 weights, fused) ----------------
__global__ __launch_bounds__(256) void cvt_all(
    const float* __restrict__ x, const float* __restrict__ wq,
    const float* __restrict__ wk, const float* __restrict__ wv,
    const float* __restrict__ wfc, bf16* __restrict__ xb, bf16* __restrict__ wqb,
    bf16* __restrict__ wkb, bf16* __restrict__ wvb, bf16* __restrict__ wfcb) {
  const long NX = (long)S_LEN * HID;
  const long NW = (long)HID * HID;
  long i = ((long)blockIdx.x * 256 + threadIdx.x) * 4;
  const float* src;
  bf16* dst;
  long off;
  if (i < NX) {
    src = x; dst = xb; off = i;
  } else {
    long j = i - NX;
    int wsel = (int)(j / NW);
    off = j - (long)wsel * NW;
    src = wsel == 0 ? wq : wsel == 1 ? wk : wsel == 2 ? wv : wfc;
    dst = wsel == 0 ? wqb : wsel == 1 ? wkb : wsel == 2 ? wvb : wfcb;
  }
  float4 v = *(const float4*)(src + off);
  bf16 h0 = __float2bfloat16(v.x), h1 = __float2bfloat16(v.y);
  bf16 h2 = __float2bfloat16(v.z), h3 = __float2bfloat16(v.w);
  ushort4 o;
  o.x = *(unsigned short*)&h0; o.y = *(unsigned short*)&h1;
  o.z = *(unsigned short*)&h2; o.w = *(unsigned short*)&h3;
  *(ushort4*)(dst + off) = o;
}

// ---------------- GEMM: C[M x 768] = scale * A[M x 768] * B[768 x 768]^T ------
template <typename OT>
__global__ __launch_bounds__(256) void gemm_bt(
    const bf16* __restrict__ A, const bf16* __restrict__ B0,
    const bf16* __restrict__ B1, const bf16* __restrict__ B2,
    OT* __restrict__ C0, OT* __restrict__ C1, OT* __restrict__ C2, float qscale) {
  constexpr int K = HID;
  __shared__ __align__(16) bf16 As[128 * 32];
  __shared__ __align__(16) bf16 Bs[128 * 32];
  const int z = blockIdx.z;
  const bf16* B = (z == 0) ? B0 : (z == 1) ? B1 : B2;
  OT* C = (z == 0) ? C0 : (z == 1) ? C1 : C2;
  const float sc = (z == 0) ? qscale : 1.0f;
  const int bm = blockIdx.y, bn = blockIdx.x;
  const int t = threadIdx.x, lane = t & 63, w = t >> 6;
  const int wm = w >> 1, wn = w & 1;
  const int q4 = lane >> 4, c16 = lane & 15;
  const int srow = lane >> 2, scol = (lane & 3) * 8;
  const bf16* Ab = A + (long)bm * 128 * K;
  const bf16* Bb = B + (long)bn * 128 * K;
  f32x4 acc[4][4] = {};
  for (int k0 = 0; k0 < K; k0 += 32) {
#pragma unroll
    for (int r = 0; r < 2; ++r) {
      int rowb = r * 64 + w * 16;
      gl2lds16(Ab + (long)(rowb + srow) * K + k0 + scol, &As[rowb * 32]);
      gl2lds16(Bb + (long)(rowb + srow) * K + k0 + scol, &Bs[rowb * 32]);
    }
    __syncthreads();
    short8 af[4], bfv[4];
#pragma unroll
    for (int i = 0; i < 4; ++i)
      af[i] = *(const short8*)&As[(wm * 64 + i * 16 + c16) * 32 + q4 * 8];
#pragma unroll
    for (int j = 0; j < 4; ++j)
      bfv[j] = *(const short8*)&Bs[(wn * 64 + j * 16 + c16) * 32 + q4 * 8];
#pragma unroll
    for (int i = 0; i < 4; ++i)
#pragma unroll
      for (int j = 0; j < 4; ++j)
        acc[i][j] = mfma_bf16(af[i], bfv[j], acc[i][j]);
    __syncthreads();
  }
  const long crow0 = (long)bm * 128 + wm * 64;
  const int ccol0 = bn * 128 + wn * 64;
#pragma unroll
  for (int i = 0; i < 4; ++i)
#pragma unroll
    for (int j = 0; j < 4; ++j)
#pragma unroll
      for (int r = 0; r < 4; ++r) {
        long row = crow0 + i * 16 + q4 * 4 + r;
        int col = ccol0 + j * 16 + c16;
        storeC(C, row * HID + col, sc * acc[i][j][r]);
      }
}

// ---------------- final GEMM: 128x64 tile ----------------
__global__ __launch_bounds__(256) void gemm_fc(const bf16* __restrict__ A,
                                               const bf16* __restrict__ B,
                                               float* __restrict__ C) {
  __shared__ __align__(16) bf16 As[128 * 32];
  __shared__ __align__(16) bf16 Bs[64 * 32];
  const int bm = blockIdx.y, bn = blockIdx.x;
  const int t = threadIdx.x, lane = t & 63, w = t >> 6;
  const int q4 = lane >> 4, c16 = lane & 15;
  const int srow = lane >> 2, scol = (lane & 3) * 8;
  const bf16* Ab = A + (long)bm * 128 * HID;
  const bf16* Bb = B + (long)bn * 64 * HID;
  f32x4 acc[2][4] = {};
  for (int k0 = 0; k0 < HID; k0 += 32) {
#pragma unroll
    for (int r = 0; r < 2; ++r) {
      int rowb = w * 32 + r * 16;
      gl2lds16(Ab + (long)(rowb + srow) * HID + k0 + scol, &As[rowb * 32]);
    }
    gl2lds16(Bb + (long)(w * 16 + srow) * HID + k0 + scol, &Bs[w * 16 * 32]);
    __syncthreads();
    short8 af[2], bfv[4];
#pragma unroll
    for (int i = 0; i < 2; ++i)
      af[i] = *(const short8*)&As[(w * 32 + i * 16 + c16) * 32 + q4 * 8];
#pragma unroll
    for (int j = 0; j < 4; ++j)
      bfv[j] = *(const short8*)&Bs[(j * 16 + c16) * 32 + q4 * 8];
#pragma unroll
    for (int i = 0; i < 2; ++i)
#pragma unroll
      for (int j = 0; j < 4; ++j)
        acc[i][j] = mfma_bf16(af[i], bfv[j], acc[i][j]);
    __syncthreads();
  }
#pragma unroll
  for (int i = 0; i < 2; ++i)
#pragma unroll
    for (int j = 0; j < 4; ++j)
#pragma unroll
      for (int r = 0; r < 4; ++r) {
        long row = (long)bm * 128 + w * 32 + i * 16 + q4 * 4 + r;
        int col = bn * 64 + j * 16 + c16;
        C[row * HID + col] = acc[i][j][r];
      }
}

// ---------------- V transpose: [4096][768] -> [768][4096] ----------------
__global__ __launch_bounds__(256) void transpose_v(const bf16* __restrict__ V,
                                                   bf16* __restrict__ Vt) {
  __shared__ unsigned short tile[64][65];
  const int bs = blockIdx.x * 64;
  const int be = blockIdx.y * 64;
  const int t = threadIdx.x;
#pragma unroll
  for (int p = 0; p < 4; ++p) {
    int i = p * 256 + t;
    int r = i >> 4;
    int c = (i & 15) * 4;
    ushort4 v = *(const ushort4*)((const unsigned short*)V + (long)(bs + r) * HID + be + c);
    tile[r][c] = v.x; tile[r][c + 1] = v.y; tile[r][c + 2] = v.z; tile[r][c + 3] = v.w;
  }
  __syncthreads();
#pragma unroll
  for (int p = 0; p < 4; ++p) {
    int i = p * 256 + t;
    int r = i >> 4;
    int c = (i & 15) * 4;
    ushort4 v;
    v.x = tile[c][r]; v.y = tile[c + 1][r]; v.z = tile[c + 2][r]; v.w = tile[c + 3][r];
    *(ushort4*)((unsigned short*)Vt + (long)(be + r) * S_LEN + bs + c) = v;
  }
}

// ---------------- flash attention v5: BKV=128, 1 barrier/iter, no split -------
// Grid (64 qt, 12 h) = 768 blocks = exactly 3/CU co-resident: NO dispatch tail
// (the v4 killer). Per iter: wave w computes S^T rows kv=w*32..+32 (2 row-frags
// x 2 kchunks x 4 q-frags = 16 MFMA), exp2+pack (packed cvt), P into the
// XOR-swizzled double-buffered Ps, ONE lgkm-only barrier, then PV d-split
// (V^T rows d=w*16..+16, kv k=128: 16 MFMA). K frags reloaded right after
// their last use, V frags after PV: next-gen global loads in flight across
// the barrier. 32 barriers per block (vs 128 in v3).
__global__ __launch_bounds__(256, 3) void flash_attn(const bf16* __restrict__ Q,
                                                     const bf16* __restrict__ Kg,
                                                     const bf16* __restrict__ Vt,
                                                     bf16* __restrict__ O) {
  __shared__ __align__(16) bf16 Ps[2][64 * 128];  // [q][kv-swizzled], 32 KB
  __shared__ float Lred[4][64];
  const int qt = blockIdx.x, h = blockIdx.y;
  const int t = threadIdx.x, lane = t & 63, w = t >> 6;
  const int q4 = lane >> 4, c16 = lane & 15;
  const int s0 = qt * 64;

  // Q B-frags, loop-invariant: row q = s0 + j*16 + c16, k-chunk = ks*32 + q4*8
  short8 qf[2][4];
  {
    const bf16* Qb = Q + (long)(s0 + c16) * HID + h * HL + q4 * 8;
#pragma unroll
    for (int j = 0; j < 4; ++j)
#pragma unroll
      for (int ks = 0; ks < 2; ++ks)
        qf[ks][j] = *(const short8*)(Qb + (long)j * 16 * HID + ks * 32);
  }
  // K A-frags: row kv = kt*128 + w*32 + rr*16 + c16, k = ks*32 + q4*8
  const bf16* kp = Kg + (long)(w * 32 + c16) * HID + h * HL + q4 * 8;
  // V^T A-frags: row d = w*16 + c16, k (kv) = kt*128 + kc*32 + q4*8
  const bf16* vp = Vt + (long)(h * HL + w * 16 + c16) * S_LEN + q4 * 8;

  float l_part[4] = {0.f, 0.f, 0.f, 0.f};
  f32x4 o_acc[4] = {};
  short8 kf[2][2], vf[4];
#pragma unroll
  for (int rr = 0; rr < 2; ++rr)
#pragma unroll
    for (int ks = 0; ks < 2; ++ks)
      kf[rr][ks] = *(const short8*)(kp + (long)rr * 16 * HID + ks * 32);
#pragma unroll
  for (int kc = 0; kc < 4; ++kc) vf[kc] = *(const short8*)(vp + kc * 32);

  for (int kt = 0; kt < S_LEN / 128; ++kt) {
    bf16* Pb = Ps[kt & 1];
    // ---- S^T = K . Q^T : D[kv (wave's 32)][q 64] ----
    f32x4 sacc[2][4] = {};
#pragma unroll
    for (int rr = 0; rr < 2; ++rr)
#pragma unroll
      for (int ks = 0; ks < 2; ++ks)
#pragma unroll
        for (int j = 0; j < 4; ++j)
          sacc[rr][j] = mfma_bf16(kf[rr][ks], qf[ks][j], sacc[rr][j]);

    // ---- prefetch next K frags (kf just had its last use) ----
    const bf16* kpn = (kt == S_LEN / 128 - 1) ? kp : kp + 128 * HID;
#pragma unroll
    for (int rr = 0; rr < 2; ++rr)
#pragma unroll
      for (int ks = 0; ks < 2; ++ks)
        kf[rr][ks] = *(const short8*)(kpn + (long)rr * 16 * HID + ks * 32);
    kp = kpn;

    // ---- p = exp2(s); partial l; P -> LDS (XOR-swizzled, b64 writes) ----
#pragma unroll
    for (int rr = 0; rr < 2; ++rr) {
      const int wch = ((w * 4 + rr * 2 + (q4 >> 1)));
#pragma unroll
      for (int j = 0; j < 4; ++j) {
        float p0 = __builtin_amdgcn_exp2f(sacc[rr][j][0]);
        float p1 = __builtin_amdgcn_exp2f(sacc[rr][j][1]);
        float p2 = __builtin_amdgcn_exp2f(sacc[rr][j][2]);
        float p3 = __builtin_amdgcn_exp2f(sacc[rr][j][3]);
        l_part[j] += (p0 + p1) + (p2 + p3);
        __hip_bfloat162 a01 = __float22bfloat162_rn(float2{p0, p1});
        __hip_bfloat162 a23 = __float22bfloat162_rn(float2{p2, p3});
        int2 pk;
        pk.x = *(int*)&a01;
        pk.y = *(int*)&a23;
        // Ps[q = j*16+c16][kv-chunk (wch ^ c16), half q4&1]
        *(int2*)&Pb[(j * 16 + c16) * 128 + (wch ^ c16) * 8 + (q4 & 1) * 4] = pk;
      }
    }
    BAR();  // P visible; K prefetch vmcnt NOT drained

    // ---- O^T += V^T . P^T : D[d (wave's 16)][q 64], kv k-dim = 128 ----
#pragma unroll
    for (int kc = 0; kc < 4; ++kc) {
#pragma unroll
      for (int j = 0; j < 4; ++j) {
        short8 pf = *(const short8*)&Pb[(j * 16 + c16) * 128 + ((kc * 4 + q4) ^ c16) * 8];
        o_acc[j] = mfma_bf16(vf[kc], pf, o_acc[j]);
      }
    }
    // ---- prefetch next V frags (vf just had its last use) ----
    const bf16* vpn = (kt == S_LEN / 128 - 1) ? vp : vp + 128;
#pragma unroll
    for (int kc = 0; kc < 4; ++kc) vf[kc] = *(const short8*)(vpn + kc * 32);
    vp = vpn;
    // no second barrier: next iter writes the other Ps buffer
  }

  // ---- l reduction: quad-sum over kv then cross-wave via LDS ----
#pragma unroll
  for (int j = 0; j < 4; ++j) {
    float s = l_part[j];
    s += __shfl_xor(s, 16, 64);
    s += __shfl_xor(s, 32, 64);
    Lred[w][j * 16 + c16] = s;
  }
  __syncthreads();
#pragma unroll
  for (int j = 0; j < 4; ++j) {
    int q = j * 16 + c16;
    float lt = Lred[0][q] + Lred[1][q] + Lred[2][q] + Lred[3][q];
    float rl = 1.0f / lt;
    float v0 = o_acc[j][0] * rl, v1 = o_acc[j][1] * rl;
    float v2 = o_acc[j][2] * rl, v3 = o_acc[j][3] * rl;
    bf16 b0 = __float2bfloat16(v0), b1 = __float2bfloat16(v1);
    bf16 b2 = __float2bfloat16(v2), b3 = __float2bfloat16(v3);
    short4 pk;
    pk.x = *(short*)&b0; pk.y = *(short*)&b1; pk.z = *(short*)&b2; pk.w = *(short*)&b3;
    // O[s0 + q][h*64 + d], d = w*16 + q4*4 + r
    *(short4*)&O[(long)(s0 + q) * HID + h * HL + w * 16 + q4 * 4] = pk;
  }
}

extern "C" void kernel_launch(void* const* d_in, const int* in_sizes, int n_in,
                              void* d_out, int out_size, void* d_ws, size_t ws_size,
                              hipStream_t stream) {
  const float* x = (const float*)d_in[0];
  const float* wq = (const float*)d_in[1];
  const float* wk = (const float*)d_in[2];
  const float* wv = (const float*)d_in[3];
  const float* wfc = (const float*)d_in[4];
  float* out = (float*)d_out;

  const long NBIG = (long)S_LEN * HID * sizeof(bf16);
  const long NWB = (long)HID * HID * sizeof(bf16);
  char* p = (char*)d_ws;
  bf16* xb = (bf16*)p;   p += NBIG;
  bf16* wqb = (bf16*)p;  p += NWB;
  bf16* wkb = (bf16*)p;  p += NWB;
  bf16* wvb = (bf16*)p;  p += NWB;
  bf16* wfcb = (bf16*)p; p += NWB;
  bf16* Qb = (bf16*)p;   p += NBIG;
  bf16* Kb = (bf16*)p;   p += NBIG;
  bf16* Vb = (bf16*)p;   p += NBIG;
  bf16* Vtb = (bf16*)p;  p += NBIG;
  bf16* Ob = (bf16*)p;   p += NBIG;

  const float c1 = 0.125f * 1.44269504088896340736f;  // softmax scale * log2(e)

  const long total4 = ((long)S_LEN * HID + 4L * HID * HID) / 4;
  cvt_all<<<(int)(total4 / 256), 256, 0, stream>>>(x, wq, wk, wv, wfc, xb, wqb, wkb,
                                                   wvb, wfcb);
  gemm_bt<bf16><<<dim3(HID / 128, S_LEN / 128, 3), 256, 0, stream>>>(
      xb, wqb, wkb, wvb, Qb, Kb, Vb, c1);
  transpose_v<<<dim3(S_LEN / 64, HID / 64), 256, 0, stream>>>(Vb, Vtb);
  flash_attn<<<dim3(S_LEN / 64, NHEAD), 256, 0, stream>>>(Qb, Kb, Vtb, Ob);
  gemm_fc<<<dim3(HID / 64, S_LEN / 128), 256, 0, stream>>>(Ob, wfcb, out);
}